// Round 1
// baseline (232.542 us; speedup 1.0000x reference)
//
#include <hip/hip_runtime.h>
#include <math.h>

// RFGCN gcnLayer fused kernel.
// Refactor: in_t = (A^T X) W_in + deg_in * b_in ; gate = (A^T X) wg_in + deg_in * bg_in
//           out_t = (A   X) W_out + deg_out* b_out; gate = (A   X) wg_out+ deg_out* bg_out
// One block per (batch, 64-row i-tile); aggregates Y_in/Y_out for all L labels over
// j-tiles with X tile shared in LDS, then a small per-block D x D epilogue GEMM.

constexpr int Ssz = 512, Dsz = 64, Lsz = 4, Bsz = 32;
constexpr int TI = 64, TJ = 64;

// LDS layout (floats)
constexpr int XPs = 68;                    // X tile stride (pad, keeps float4 align)
constexpr int XP  = 0;                     // [64][68]
constexpr int AAs = 65;
constexpr int AA  = XP + 64 * XPs;         // adj in-tile  [64][65]  (adj[j0+r][i0+c])
constexpr int ABs = 65;
constexpr int AB  = AA + 64 * AAs;         // adj out-tile [64][65]  (adj[i0+r][j0+c])
constexpr int WGo = AB + 64 * ABs;         // gate weight vector [64]
constexpr int BBo = WGo + 64;              // bias vector [64]
constexpr int SM_TOTAL = BBo + 64;
// epilogue aliases (main-loop tiles dead by then)
constexpr int YBs = 69;                    // stride 69 -> banks (5i+c)%32, conflict-free
constexpr int YB  = AA;                    // [64][69] over AA..AB region (4416 <= 8320)
constexpr int WBs = 68;
constexpr int WB  = XP;                    // [64][68] over XP (4352)

__global__ __launch_bounds__(1024)
void rfgcn_fused(const float* __restrict__ X,      // [B][S][D]
                 const int*   __restrict__ adj,    // [L][B][S][S] (0/1; nonzero test)
                 const float* __restrict__ nw,     // [B]
                 const float* __restrict__ W_in,   // [L][D][D]
                 const float* __restrict__ b_in,   // [L][D]
                 const float* __restrict__ wg_in,  // [L][D]
                 const float* __restrict__ bg_in,  // [L]
                 const float* __restrict__ W_out,
                 const float* __restrict__ b_out,
                 const float* __restrict__ wg_out,
                 const float* __restrict__ bg_out,
                 float* __restrict__ out)          // [B][S][D]
{
    __shared__ float sm[SM_TOTAL];
    const int tid   = threadIdx.x;
    const int batch = blockIdx.y;
    const int i0    = blockIdx.x * TI;
    const int i     = tid & 63;     // output row within tile (lane)
    const int g     = tid >> 6;     // 0..15 column group
    const int cb    = g * 4;        // 4 columns per thread

    float4 yin[Lsz], yout[Lsz];
    float  degin[Lsz], degout[Lsz];
#pragma unroll
    for (int l = 0; l < Lsz; ++l) {
        yin[l]  = float4{0.f, 0.f, 0.f, 0.f};
        yout[l] = float4{0.f, 0.f, 0.f, 0.f};
        degin[l] = 0.f; degout[l] = 0.f;
    }

    const float* Xb = X + (size_t)batch * Ssz * Dsz;

    for (int jt = 0; jt < Ssz / TJ; ++jt) {
        const int j0 = jt * TJ;
#pragma unroll
        for (int l = 0; l < Lsz; ++l) {
            __syncthreads();   // previous tile's consumers done
            if (l == 0) {
#pragma unroll
                for (int k = 0; k < 4; ++k) {
                    int m = tid + k * 1024; int r = m >> 6, c = m & 63;
                    sm[XP + r * XPs + c] = Xb[(j0 + r) * Dsz + c];
                }
            }
            const int* adjlb = adj + ((size_t)l * Bsz + batch) * Ssz * Ssz;
#pragma unroll
            for (int k = 0; k < 4; ++k) {
                int m = tid + k * 1024; int r = m >> 6, c = m & 63;
                // nonzero-test: correct for both int32{0,1} and f32{0,1.0f} bit patterns
                sm[AA + r * AAs + c] = (adjlb[(size_t)(j0 + r) * Ssz + (i0 + c)] != 0) ? 1.f : 0.f;
                sm[AB + r * ABs + c] = (adjlb[(size_t)(i0 + r) * Ssz + (j0 + c)] != 0) ? 1.f : 0.f;
            }
            __syncthreads();

            float  di = 0.f, dv = 0.f;
            float4 accI = yin[l], accO = yout[l];
#pragma unroll 8
            for (int j = 0; j < TJ; ++j) {
                const float a  = sm[AA + j * AAs + i];   // adj[j0+j][i0+i]  (in)
                const float bo = sm[AB + i * ABs + j];   // adj[i0+i][j0+j]  (out)
                const float4 xv = *reinterpret_cast<const float4*>(&sm[XP + j * XPs + cb]);
                di += a; dv += bo;
                accI.x += a * xv.x;  accI.y += a * xv.y;
                accI.z += a * xv.z;  accI.w += a * xv.w;
                accO.x += bo * xv.x; accO.y += bo * xv.y;
                accO.z += bo * xv.z; accO.w += bo * xv.w;
            }
            yin[l] = accI; yout[l] = accO;
            degin[l] += di; degout[l] += dv;
        }
    }

    // ---- epilogue: per (l, dir): t = Y*W + deg*b; gate = Y*wg + deg*bg; fin += t*sigmoid(gate)
    float4 fin = float4{0.f, 0.f, 0.f, 0.f};
#pragma unroll
    for (int l = 0; l < Lsz; ++l) {
#pragma unroll
        for (int dir = 0; dir < 2; ++dir) {
            __syncthreads();   // previous epilogue/main reads done before overwrite
            const float4 yv4 = dir ? yout[l] : yin[l];
            sm[YB + i * YBs + cb + 0] = yv4.x;
            sm[YB + i * YBs + cb + 1] = yv4.y;
            sm[YB + i * YBs + cb + 2] = yv4.z;
            sm[YB + i * YBs + cb + 3] = yv4.w;
            const float* Wp  = (dir ? W_out  : W_in)  + l * Dsz * Dsz;
            const float* bp  = (dir ? b_out  : b_in)  + l * Dsz;
            const float* wgp = (dir ? wg_out : wg_in) + l * Dsz;
            const float  bgs = (dir ? bg_out : bg_in)[l];
#pragma unroll
            for (int k = 0; k < 4; ++k) {
                int m = tid + k * 1024; int r = m >> 6, c = m & 63;
                sm[WB + r * WBs + c] = Wp[r * Dsz + c];
            }
            if (tid < 64)       sm[WGo + tid]      = wgp[tid];
            else if (tid < 128) sm[BBo + tid - 64] = bp[tid - 64];
            __syncthreads();

            const float dg = dir ? degout[l] : degin[l];
            float4 t;
            t.x = dg * sm[BBo + cb + 0];
            t.y = dg * sm[BBo + cb + 1];
            t.z = dg * sm[BBo + cb + 2];
            t.w = dg * sm[BBo + cb + 3];
            float gate = dg * bgs;
#pragma unroll 8
            for (int c = 0; c < Dsz; ++c) {
                const float yv = sm[YB + i * YBs + c];
                const float4 wv = *reinterpret_cast<const float4*>(&sm[WB + c * WBs + cb]);
                t.x += yv * wv.x; t.y += yv * wv.y;
                t.z += yv * wv.z; t.w += yv * wv.w;
                gate += yv * sm[WGo + c];
            }
            const float sg = 1.f / (1.f + expf(-gate));
            fin.x += t.x * sg; fin.y += t.y * sg;
            fin.z += t.z * sg; fin.w += t.w * sg;
        }
    }

    // ---- combine: (x + sum) / (3 * num_words[b])
    const float inv = 1.f / (3.f * nw[batch]);
    const float4 xv = *reinterpret_cast<const float4*>(&Xb[(i0 + i) * Dsz + cb]);
    float4 o;
    o.x = (xv.x + fin.x) * inv;
    o.y = (xv.y + fin.y) * inv;
    o.z = (xv.z + fin.z) * inv;
    o.w = (xv.w + fin.w) * inv;
    *reinterpret_cast<float4*>(out + ((size_t)batch * Ssz + i0 + i) * Dsz + cb) = o;
}

extern "C" void kernel_launch(void* const* d_in, const int* in_sizes, int n_in,
                              void* d_out, int out_size, void* d_ws, size_t ws_size,
                              hipStream_t stream)
{
    const float* X      = (const float*)d_in[0];
    const int*   adj    = (const int*)  d_in[1];
    const float* nw     = (const float*)d_in[2];
    const float* W_in   = (const float*)d_in[3];
    const float* b_in   = (const float*)d_in[4];
    const float* wg_in  = (const float*)d_in[5];
    const float* bg_in  = (const float*)d_in[6];
    const float* W_out  = (const float*)d_in[7];
    const float* b_out  = (const float*)d_in[8];
    const float* wg_out = (const float*)d_in[9];
    const float* bg_out = (const float*)d_in[10];
    float* out = (float*)d_out;

    dim3 grid(Ssz / TI, Bsz);   // (8, 32) = 256 blocks
    dim3 block(1024);
    hipLaunchKernelGGL(rfgcn_fused, grid, block, 0, stream,
                       X, adj, nw, W_in, b_in, wg_in, bg_in,
                       W_out, b_out, wg_out, bg_out, out);
}

// Round 4
// 78.775 us; speedup vs baseline: 2.9520x; 2.9520x over previous
//
#include <hip/hip_runtime.h>
#include <math.h>

typedef short short8 __attribute__((ext_vector_type(8)));
typedef float f32x4  __attribute__((ext_vector_type(4)));

constexpr int Ssz = 512, Dsz = 64, Lsz = 4, Bsz = 32;
constexpr int TI = 64, TJ = 64;   // i-tile, j-chunk
constexpr int SJ = 72;            // LDS row stride in bf16 elems (144 B = 36 dwords == 4 mod 32 -> bank-uniform b128)

// LDS byte offsets (main phase)
constexpr int XH_off = 0;                        // [64 d][SJ] bf16 hi(X^T)
constexpr int XL_off = XH_off + 64 * SJ * 2;     // lo(X^T)
constexpr int AI_off = XL_off + 64 * SJ * 2;     // 4 x [64 i][SJ]  AI[l][i][j] = A[j0+j][i0+i] (j-block XOR-swizzled)
constexpr int AO_off = AI_off + 4 * 64 * SJ * 2; // 4 x [64 i][SJ]  AO[l][i][j] = A[i0+i][j0+j]
constexpr int SMEM_BYTES = AO_off + 4 * 64 * SJ * 2;  // 92160 B

// epilogue aliases (float-indexed, overlay on main region — main tiles dead by then)
constexpr int YBs = 69;                           // 69 == 5 mod 32 -> conflict-free column reads
constexpr int YB_f = 0;                           // [64][69] f32
constexpr int WBs = 68;
constexpr int WB_f = YB_f + 64 * YBs;             // [64][68] f32
constexpr int DG_f = WB_f + 64 * WBs;             // [64] deg
constexpr int WG_f = DG_f + 64;                   // [64] gate weights
constexpr int BB_f = WG_f + 64;                   // [64] bias

__device__ __forceinline__ unsigned short f2bf(float x) {
    union { float f; unsigned u; } v; v.f = x;
    unsigned r = v.u + 0x7FFFu + ((v.u >> 16) & 1u);   // RNE
    return (unsigned short)(r >> 16);
}

__global__ __launch_bounds__(512, 2)
void rfgcn_mfma(const float* __restrict__ X,      // [B][S][D]
                const int*   __restrict__ adj,    // [L][B][S][S]
                const float* __restrict__ nw,     // [B]
                const float* __restrict__ W_in,   // [L][D][D] (row = d_in)
                const float* __restrict__ b_in,   // [L][D]
                const float* __restrict__ wg_in,  // [L][D]
                const float* __restrict__ bg_in,  // [L]
                const float* __restrict__ W_out,
                const float* __restrict__ b_out,
                const float* __restrict__ wg_out,
                const float* __restrict__ bg_out,
                float* __restrict__ out)
{
    __shared__ __align__(16) char smem[SMEM_BYTES];
    short* sm16 = (short*)smem;
    float* smf  = (float*)smem;

    const int tid  = threadIdx.x;
    const int b    = blockIdx.y;
    const int i0   = blockIdx.x * TI;
    const int w    = tid >> 6;      // wave 0..7
    const int lane = tid & 63;
    const int dir  = w & 1;         // 0 = in (A^T), 1 = out (A)
    const int sw   = w >> 1;        // 16-row strip 0..3
    const int lm   = lane & 15;
    const int lg   = lane >> 4;     // k-group 0..3

    f32x4 acc[Lsz][4];              // [label][n-tile]
    f32x4 dacc[Lsz];                // degree accumulator
#pragma unroll
    for (int l = 0; l < Lsz; ++l) {
#pragma unroll
        for (int nt = 0; nt < 4; ++nt) acc[l][nt] = (f32x4){0.f, 0.f, 0.f, 0.f};
        dacc[l] = (f32x4){0.f, 0.f, 0.f, 0.f};
    }
    const short8 ones = {(short)0x3F80, (short)0x3F80, (short)0x3F80, (short)0x3F80,
                         (short)0x3F80, (short)0x3F80, (short)0x3F80, (short)0x3F80};

    const float* Xb = X + (size_t)b * Ssz * Dsz;

    for (int jc = 0; jc < Ssz / TJ; ++jc) {
        const int j0 = jc * TJ;
        __syncthreads();   // previous chunk's fragment reads done

        // ---- stage X^T hi/lo: thread owns column d=lane, rows j0+8w..+7 (coalesced 256B rows)
        {
            const int d = lane;
            float xv[8];
#pragma unroll
            for (int s = 0; s < 8; ++s) xv[s] = Xb[(size_t)(j0 + 8 * w + s) * Dsz + d];
            short8 hi, lo;
#pragma unroll
            for (int s = 0; s < 8; ++s) {
                unsigned short h = f2bf(xv[s]);
                union { unsigned u; float f; } hf; hf.u = ((unsigned)h) << 16;
                hi[s] = (short)h;
                lo[s] = (short)f2bf(xv[s] - hf.f);
            }
            const int blk = w ^ ((d >> 3) & 7);
            *(short8*)(sm16 + XH_off / 2 + d * SJ + blk * 8) = hi;
            *(short8*)(sm16 + XL_off / 2 + d * SJ + blk * 8) = lo;
        }
        // ---- stage AI (transposed adjacency): thread owns col i=lane, rows j0+8w..+7
#pragma unroll
        for (int l = 0; l < Lsz; ++l) {
            const int* Ab = adj + ((size_t)l * Bsz + b) * Ssz * Ssz;
            int iv[8];
#pragma unroll
            for (int s = 0; s < 8; ++s) iv[s] = Ab[(size_t)(j0 + 8 * w + s) * Ssz + i0 + lane];
            short8 v;
#pragma unroll
            for (int s = 0; s < 8; ++s) v[s] = iv[s] ? (short)0x3F80 : (short)0;
            const int blk = w ^ ((lane >> 3) & 7);
            *(short8*)(sm16 + AI_off / 2 + l * 64 * SJ + lane * SJ + blk * 8) = v;
        }
        // ---- stage AO (direct adjacency): thread owns row r=tid>>3, j-block c8=tid&7
#pragma unroll
        for (int l = 0; l < Lsz; ++l) {
            const int* Ab = adj + ((size_t)l * Bsz + b) * Ssz * Ssz;
            const int r = tid >> 3, c8 = tid & 7;
            const int4 p0 = *(const int4*)&Ab[(size_t)(i0 + r) * Ssz + j0 + 8 * c8];
            const int4 p1 = *(const int4*)&Ab[(size_t)(i0 + r) * Ssz + j0 + 8 * c8 + 4];
            short8 v;
            v[0] = p0.x ? (short)0x3F80 : (short)0;  v[1] = p0.y ? (short)0x3F80 : (short)0;
            v[2] = p0.z ? (short)0x3F80 : (short)0;  v[3] = p0.w ? (short)0x3F80 : (short)0;
            v[4] = p1.x ? (short)0x3F80 : (short)0;  v[5] = p1.y ? (short)0x3F80 : (short)0;
            v[6] = p1.z ? (short)0x3F80 : (short)0;  v[7] = p1.w ? (short)0x3F80 : (short)0;
            *(short8*)(sm16 + AO_off / 2 + l * 64 * SJ + r * SJ + c8 * 8) = v;
        }
        __syncthreads();

        // ---- 2 K-steps of 32
#pragma unroll
        for (int ks = 0; ks < 2; ++ks) {
            short8 bh[4], bl[4];
#pragma unroll
            for (int nt = 0; nt < 4; ++nt) {
                const int d = nt * 16 + lm;
                const int blk = (4 * ks + lg) ^ ((d >> 3) & 7);
                bh[nt] = *(const short8*)(sm16 + XH_off / 2 + d * SJ + blk * 8);
                bl[nt] = *(const short8*)(sm16 + XL_off / 2 + d * SJ + blk * 8);
            }
            const int i_loc = 16 * sw + lm;
#pragma unroll
            for (int l = 0; l < Lsz; ++l) {
                short8 af;
                if (dir == 0) {
                    const int blk = (4 * ks + lg) ^ ((i_loc >> 3) & 7);
                    af = *(const short8*)(sm16 + AI_off / 2 + l * 64 * SJ + i_loc * SJ + blk * 8);
                } else {
                    af = *(const short8*)(sm16 + AO_off / 2 + l * 64 * SJ + i_loc * SJ + (4 * ks + lg) * 8);
                }
#pragma unroll
                for (int nt = 0; nt < 4; ++nt) {
                    acc[l][nt] = __builtin_amdgcn_mfma_f32_16x16x32_bf16(af, bh[nt], acc[l][nt], 0, 0, 0);
                    acc[l][nt] = __builtin_amdgcn_mfma_f32_16x16x32_bf16(af, bl[nt], acc[l][nt], 0, 0, 0);
                }
                dacc[l] = __builtin_amdgcn_mfma_f32_16x16x32_bf16(af, ones, dacc[l], 0, 0, 0);
            }
        }
    }

    // ================= epilogue: t = Y*W + deg*b; gate = Y*wg + deg*bg; fin += t*sigmoid(gate)
    const int ei  = tid & 63;          // output row within tile
    const int ecb = (tid >> 6) * 8;    // 8-column group
    float fin[8];
#pragma unroll
    for (int q = 0; q < 8; ++q) fin[q] = 0.f;

#pragma unroll
    for (int l = 0; l < Lsz; ++l) {
#pragma unroll
        for (int d2 = 0; d2 < 2; ++d2) {
            __syncthreads();   // previous consumers done before overwrite
            if (dir == d2) {   // this wave owns (strip sw, dir d2) rows of acc[l]
#pragma unroll
                for (int nt = 0; nt < 4; ++nt)
#pragma unroll
                    for (int r = 0; r < 4; ++r)
                        smf[YB_f + (16 * sw + 4 * lg + r) * YBs + nt * 16 + lm] = acc[l][nt][r];
                if (lm == 0)
#pragma unroll
                    for (int r = 0; r < 4; ++r)
                        smf[DG_f + 16 * sw + 4 * lg + r] = dacc[l][r];
            }
            // stage W (all threads)
            const float* Wp = (d2 ? W_out : W_in) + l * Dsz * Dsz;
            {
                const int r = tid >> 3, c8 = tid & 7;
                *(float4*)&smf[WB_f + r * WBs + 8 * c8]     = *(const float4*)&Wp[r * Dsz + 8 * c8];
                *(float4*)&smf[WB_f + r * WBs + 8 * c8 + 4] = *(const float4*)&Wp[r * Dsz + 8 * c8 + 4];
            }
            const float* wgp = (d2 ? wg_out : wg_in) + l * Dsz;
            const float* bp  = (d2 ? b_out  : b_in)  + l * Dsz;
            if (tid < 64)        smf[WG_f + tid]      = wgp[tid];
            else if (tid < 128)  smf[BB_f + tid - 64] = bp[tid - 64];
            const float bgs = (d2 ? bg_out : bg_in)[l];
            __syncthreads();

            const float dg = smf[DG_f + ei];
            float t[8];
#pragma unroll
            for (int q = 0; q < 8; ++q) t[q] = dg * smf[BB_f + ecb + q];
            float gate = dg * bgs;
#pragma unroll 4
            for (int e = 0; e < 64; ++e) {
                const float yv = smf[YB_f + ei * YBs + e];
                gate += yv * smf[WG_f + e];
#pragma unroll
                for (int q = 0; q < 8; ++q) t[q] += yv * smf[WB_f + e * WBs + ecb + q];
            }
            const float sg = 1.f / (1.f + expf(-gate));
#pragma unroll
            for (int q = 0; q < 8; ++q) fin[q] += t[q] * sg;
        }
    }

    const float inv = 1.f / (3.f * nw[b]);
    const float4 x0 = *(const float4*)&Xb[(size_t)(i0 + ei) * Dsz + ecb];
    const float4 x1 = *(const float4*)&Xb[(size_t)(i0 + ei) * Dsz + ecb + 4];
    float4 o0, o1;
    o0.x = (x0.x + fin[0]) * inv;  o0.y = (x0.y + fin[1]) * inv;
    o0.z = (x0.z + fin[2]) * inv;  o0.w = (x0.w + fin[3]) * inv;
    o1.x = (x1.x + fin[4]) * inv;  o1.y = (x1.y + fin[5]) * inv;
    o1.z = (x1.z + fin[6]) * inv;  o1.w = (x1.w + fin[7]) * inv;
    float* op = out + ((size_t)b * Ssz + i0 + ei) * Dsz + ecb;
    *(float4*)op       = o0;
    *(float4*)(op + 4) = o1;
}

extern "C" void kernel_launch(void* const* d_in, const int* in_sizes, int n_in,
                              void* d_out, int out_size, void* d_ws, size_t ws_size,
                              hipStream_t stream)
{
    const float* X      = (const float*)d_in[0];
    const int*   adj    = (const int*)  d_in[1];
    const float* nw     = (const float*)d_in[2];
    const float* W_in   = (const float*)d_in[3];
    const float* b_in   = (const float*)d_in[4];
    const float* wg_in  = (const float*)d_in[5];
    const float* bg_in  = (const float*)d_in[6];
    const float* W_out  = (const float*)d_in[7];
    const float* b_out  = (const float*)d_in[8];
    const float* wg_out = (const float*)d_in[9];
    const float* bg_out = (const float*)d_in[10];
    float* out = (float*)d_out;

    dim3 grid(Ssz / TI, Bsz);   // (8, 32) = 256 blocks
    dim3 block(512);
    hipLaunchKernelGGL(rfgcn_mfma, grid, block, 0, stream,
                       X, adj, nw, W_in, b_in, wg_in, bg_in,
                       W_out, b_out, wg_out, bg_out, out);
}